// Round 15
// baseline (237.956 us; speedup 1.0000x reference)
//
#include <hip/hip_runtime.h>

#define NROW 8192
#define INF  512
#define OUTF 256
#define M_ELEM (NROW * OUTF)   // 2,097,152 f32 per output matrix
#define NSTEP 32               // K-steps of 256

typedef __bf16 v8bf __attribute__((ext_vector_type(8)));
typedef __bf16 v4bf __attribute__((ext_vector_type(4)));
typedef float  v4f  __attribute__((ext_vector_type(4)));

__device__ __forceinline__ v8bf cvt_bf8(v4f u0, v4f u1) {
  v8bf v;
  v[0]=(__bf16)u0[0]; v[1]=(__bf16)u0[1]; v[2]=(__bf16)u0[2]; v[3]=(__bf16)u0[3];
  v[4]=(__bf16)u1[0]; v[5]=(__bf16)u1[1]; v[6]=(__bf16)u1[2]; v[7]=(__bf16)u1[3];
  return v;
}

// ---------------------------------------------------------------------------
// Kernel A: seq = feat @ W^T, bf16 MFMA, output in B-fragment-packed layout:
//   elem(m,o) -> (((m>>5)*16 + (o>>4))*64 + ((m>>3)&3)*16 + (o&15))*8 + (m&7)
// ---------------------------------------------------------------------------
__global__ __launch_bounds__(256) void seq_fts_kernel(
    const float* __restrict__ feat, const float* __restrict__ W,
    __bf16* __restrict__ Bp) {
  const int tid  = threadIdx.x;
  const int lane = tid & 63, w = tid >> 6;
  const int llo  = lane & 15, lhi = lane >> 4;
  const int row0 = blockIdx.x * 64;
  const int col0 = w * 64;

  v4f acc[4][4] = {};
#pragma unroll 1
  for (int kb = 0; kb < INF / 32; ++kb) {
    const int kofs = kb * 32 + lhi * 8;
    v8bf a[4], b[4];
#pragma unroll
    for (int i = 0; i < 4; ++i) {
      const float* p = feat + (size_t)(row0 + i * 16 + llo) * INF + kofs;
      a[i] = cvt_bf8(*(const v4f*)p, *(const v4f*)(p + 4));
    }
#pragma unroll
    for (int i = 0; i < 4; ++i) {
      const float* p = W + (size_t)(col0 + i * 16 + llo) * INF + kofs;
      b[i] = cvt_bf8(*(const v4f*)p, *(const v4f*)(p + 4));
    }
#pragma unroll
    for (int ri = 0; ri < 4; ++ri)
#pragma unroll
      for (int ci = 0; ci < 4; ++ci)
        acc[ri][ci] = __builtin_amdgcn_mfma_f32_16x16x32_bf16(
            a[ri], b[ci], acc[ri][ci], 0, 0, 0);
  }
#pragma unroll
  for (int ri = 0; ri < 4; ++ri)
#pragma unroll
    for (int ci = 0; ci < 4; ++ci) {
      const int mf = row0 + ri * 16 + lhi * 4;
      const int o  = col0 + ci * 16 + llo;
      size_t e = (((size_t)(mf >> 5) * 16 + (o >> 4)) * 64 +
                  ((mf >> 3) & 3) * 16 + (o & 15)) * 8 + (mf & 7);
      v4bf v;
      v[0] = (__bf16)acc[ri][ci][0]; v[1] = (__bf16)acc[ri][ci][1];
      v[2] = (__bf16)acc[ri][ci][2]; v[3] = (__bf16)acc[ri][ci][3];
      *(v4bf*)(Bp + e) = v;
    }
}

// ---------------------------------------------------------------------------
// Kernel B: out = prelu(adj @ seq + bias).
// TWO-STEP-DEEP A register pipeline: A(t+2) NT-loaded to regs at top of step
// t, swizzle-ds_written ~2 sub-steps later, read one barrier after. A stays
// continuously ~120 KB/CU in flight (vs burst-and-drain in R2..R14, whose
// duty cycle pinned every schedule at ~5 B/cy/CU). All reg loads -> compiler
// emits exact counted vmcnt; FIFO discipline: per step, all B-groups issued
// BEFORE A(t+2), so compute waits drain only A(t+1) (landed) + older B,
// never A(t+2). Raw s_barrier + lgkmcnt only (no vmcnt(0) anywhere).
// BM=64, BK=256 (1 KB extents), 8 waves (2x4), D=2 LDS (128 KB).
// VGPR budget: aA+aB 64, b[8][4] 128, acc 32, addr ~25 -> ~250 (cap 256 via
// waves_per_eu(2,2)). VGPR_Count is this round's witness.
// ---------------------------------------------------------------------------
__global__ __launch_bounds__(512, 2)
__attribute__((amdgpu_waves_per_eu(2, 2)))
void gcn_agg_kernel(
    const float* __restrict__ adjA, const float* __restrict__ adjB,
    const __bf16* __restrict__ Bp, const float* __restrict__ bias,
    const float* __restrict__ prelu_a, float* __restrict__ out) {
  const int tid  = threadIdx.x;
  const int lane = tid & 63, w = tid >> 6;
  const int llo  = lane & 15, lhi = lane >> 4;
  const int wr   = w >> 2, wc = w & 3;     // 2 row-groups x 4 col-groups
  const int row0 = blockIdx.x * 64;
  const int z    = blockIdx.y;
  const float* __restrict__ adj = z ? adjB : adjA;

  __shared__ __align__(16) char LdsA[2][65536];   // 2 x (64 rows x 1 KB)

  v4f acc[2][4] = {};
  v4f aA[8], aB[8];          // two A batches in flight (named, static)
  v8bf b[8][4];              // full-step B fragments

  auto issue_a = [&](int t, v4f (&ar)[8]) {
#pragma unroll
    for (int i = 0; i < 8; ++i) {
      const int r = w * 8 + i;
      const float* src =
          adj + (size_t)(row0 + r) * NROW + t * 256 + (lane << 2);
      ar[i] = __builtin_nontemporal_load((const v4f*)src);
    }
  };
  auto write_a = [&](int buf, v4f (&ar)[8]) {
#pragma unroll
    for (int i = 0; i < 8; ++i) {
      const int r   = w * 8 + i;
      const int key = ((r & 15) << 1) | ((r >> 3) & 1);
      *(v4f*)(&LdsA[buf][r * 1024 + ((lane ^ key) << 4)]) = ar[i];
    }
  };

  const __bf16* __restrict__ Bpw = Bp + ((size_t)(wc * 4) * 64 + lane) * 8;
  auto load_b_all = [&](int t) {
#pragma unroll
    for (int g = 0; g < 8; ++g)
#pragma unroll
      for (int ci = 0; ci < 4; ++ci)
        b[g][ci] = *(const v8bf*)(
            Bpw + ((size_t)((t * 8 + g) * 16 + ci)) * 512);
  };

  auto compute_g = [&](int buf, int kg) {
    const char* ab = &LdsA[buf][0];
    v8bf af[2];
#pragma unroll
    for (int rt = 0; rt < 2; ++rt) {
      const int r   = wr * 32 + rt * 16 + llo;
      const int key = ((r & 15) << 1) | ((r >> 3) & 1);
      const char* base = ab + r * 1024;
      v4f u0 = *(const v4f*)(base + (((kg * 8 + lhi * 2    ) ^ key) << 4));
      v4f u1 = *(const v4f*)(base + (((kg * 8 + lhi * 2 + 1) ^ key) << 4));
      af[rt] = cvt_bf8(u0, u1);
    }
#pragma unroll
    for (int ci = 0; ci < 4; ++ci)
#pragma unroll
      for (int rt = 0; rt < 2; ++rt)
        acc[rt][ci] = __builtin_amdgcn_mfma_f32_16x16x32_bf16(
            af[rt], b[kg][ci], acc[rt][ci], 0, 0, 0);
  };

  // prologue: A(0)->aA, A(1)->aB, write A(0) (compiler waits vmcnt(8))
  issue_a(0, aA);
  issue_a(1, aB);
  write_a(0, aA);
  asm volatile("s_waitcnt lgkmcnt(0)" ::: "memory");
  __builtin_amdgcn_sched_barrier(0);
  __builtin_amdgcn_s_barrier();

#pragma unroll 1
  for (int t = 0; t < NSTEP; t += 2) {
    // ---- even sub-step: compute LDS[0]=A(t); pend aB=A(t+1); free aA
    load_b_all(t);                       // B older than A(t+2) in FIFO
    __builtin_amdgcn_sched_barrier(0);
    if (t + 2 < NSTEP) issue_a(t + 2, aA);
    __builtin_amdgcn_sched_barrier(0);
#pragma unroll
    for (int g = 0; g < 8; ++g) compute_g(0, g);
    __builtin_amdgcn_sched_barrier(0);
    write_a(1, aB);                      // A(t+1) -> LDS[1] (landed: B-drain)
    asm volatile("s_waitcnt lgkmcnt(0)" ::: "memory");
    __builtin_amdgcn_sched_barrier(0);
    __builtin_amdgcn_s_barrier();
    // ---- odd sub-step: compute LDS[1]=A(t+1); pend aA=A(t+2); free aB
    load_b_all(t + 1);
    __builtin_amdgcn_sched_barrier(0);
    if (t + 3 < NSTEP) issue_a(t + 3, aB);
    __builtin_amdgcn_sched_barrier(0);
#pragma unroll
    for (int g = 0; g < 8; ++g) compute_g(1, g);
    __builtin_amdgcn_sched_barrier(0);
    if (t + 2 < NSTEP) {
      write_a(0, aA);                    // A(t+2) -> LDS[0]
      asm volatile("s_waitcnt lgkmcnt(0)" ::: "memory");
    }
    __builtin_amdgcn_sched_barrier(0);
    __builtin_amdgcn_s_barrier();
  }

  // epilogue: bias + prelu, direct store
  const float slope = prelu_a[0];
  float* __restrict__ outp = out + (size_t)z * M_ELEM;
#pragma unroll
  for (int ci = 0; ci < 4; ++ci) {
    const int o  = wc * 64 + ci * 16 + llo;
    const float bs = bias[o];
#pragma unroll
    for (int rt = 0; rt < 2; ++rt) {
      const int m = row0 + wr * 32 + rt * 16 + lhi * 4;
#pragma unroll
      for (int r = 0; r < 4; ++r) {
        float v = acc[rt][ci][r] + bs;
        outp[(size_t)(m + r) * OUTF + o] = v >= 0.f ? v : slope * v;
      }
    }
  }
}

extern "C" void kernel_launch(void* const* d_in, const int* in_sizes, int n_in,
                              void* d_out, int out_size, void* d_ws, size_t ws_size,
                              hipStream_t stream) {
  const float* feat = (const float*)d_in[0];
  const float* adj  = (const float*)d_in[1];
  const float* aug  = (const float*)d_in[2];
  const float* W    = (const float*)d_in[3];
  const float* bias = (const float*)d_in[4];
  const float* pa   = (const float*)d_in[5];
  float* out = (float*)d_out;
  __bf16* Bp = (__bf16*)d_ws;                    // 4 MB packed seq_fts

  seq_fts_kernel<<<dim3(NROW / 64), 256, 0, stream>>>(feat, W, Bp);
  gcn_agg_kernel<<<dim3(NROW / 64, 2), 512, 0, stream>>>(
      adj, aug, Bp, bias, pa, out);
}

// Round 16
// 228.039 us; speedup vs baseline: 1.0435x; 1.0435x over previous
//
#include <hip/hip_runtime.h>

#define NROW 8192
#define INF  512
#define OUTF 256
#define M_ELEM (NROW * OUTF)   // 2,097,152 f32 per output matrix
#define NSTEP 32               // K-steps of 256

typedef __bf16 v8bf __attribute__((ext_vector_type(8)));
typedef __bf16 v4bf __attribute__((ext_vector_type(4)));
typedef float  v4f  __attribute__((ext_vector_type(4)));

__device__ __forceinline__ v8bf cvt_bf8(v4f u0, v4f u1) {
  v8bf v;
  v[0]=(__bf16)u0[0]; v[1]=(__bf16)u0[1]; v[2]=(__bf16)u0[2]; v[3]=(__bf16)u0[3];
  v[4]=(__bf16)u1[0]; v[5]=(__bf16)u1[1]; v[6]=(__bf16)u1[2]; v[7]=(__bf16)u1[3];
  return v;
}

// ---------------------------------------------------------------------------
// Kernel A: seq = feat @ W^T, bf16 MFMA, output in B-fragment-packed layout:
//   elem(m,o) -> (((m>>5)*16 + (o>>4))*64 + ((m>>3)&3)*16 + (o&15))*8 + (m&7)
// ---------------------------------------------------------------------------
__global__ __launch_bounds__(256) void seq_fts_kernel(
    const float* __restrict__ feat, const float* __restrict__ W,
    __bf16* __restrict__ Bp) {
  const int tid  = threadIdx.x;
  const int lane = tid & 63, w = tid >> 6;
  const int llo  = lane & 15, lhi = lane >> 4;
  const int row0 = blockIdx.x * 64;
  const int col0 = w * 64;

  v4f acc[4][4] = {};
#pragma unroll 1
  for (int kb = 0; kb < INF / 32; ++kb) {
    const int kofs = kb * 32 + lhi * 8;
    v8bf a[4], b[4];
#pragma unroll
    for (int i = 0; i < 4; ++i) {
      const float* p = feat + (size_t)(row0 + i * 16 + llo) * INF + kofs;
      a[i] = cvt_bf8(*(const v4f*)p, *(const v4f*)(p + 4));
    }
#pragma unroll
    for (int i = 0; i < 4; ++i) {
      const float* p = W + (size_t)(col0 + i * 16 + llo) * INF + kofs;
      b[i] = cvt_bf8(*(const v4f*)p, *(const v4f*)(p + 4));
    }
#pragma unroll
    for (int ri = 0; ri < 4; ++ri)
#pragma unroll
      for (int ci = 0; ci < 4; ++ci)
        acc[ri][ci] = __builtin_amdgcn_mfma_f32_16x16x32_bf16(
            a[ri], b[ci], acc[ri][ci], 0, 0, 0);
  }
#pragma unroll
  for (int ri = 0; ri < 4; ++ri)
#pragma unroll
    for (int ci = 0; ci < 4; ++ci) {
      const int mf = row0 + ri * 16 + lhi * 4;
      const int o  = col0 + ci * 16 + llo;
      size_t e = (((size_t)(mf >> 5) * 16 + (o >> 4)) * 64 +
                  ((mf >> 3) & 3) * 16 + (o & 15)) * 8 + (mf & 7);
      v4bf v;
      v[0] = (__bf16)acc[ri][ci][0]; v[1] = (__bf16)acc[ri][ci][1];
      v[2] = (__bf16)acc[ri][ci][2]; v[3] = (__bf16)acc[ri][ci][3];
      *(v4bf*)(Bp + e) = v;
    }
}

// ---------------------------------------------------------------------------
// Kernel B: out = prelu(adj @ seq + bias).
// MANY-WAVE STREAMING (m13 regime): BM=32, 8 waves each own 32 rows x 32 cols
// -> acc 16 VGPR, ZERO B-duplication (distinct cols per wave, L2 traffic
// halved). BK=256 keeps 1 KB extents. D=2 x 32 KB LDS = 64 KB -> 2 blocks/CU
// = 16 waves/CU. A reg-staged depth-2 (aA/aB); B two upfront chunks.
// FIFO per sub-step: [c0,c1 (B), A(t+2)] -> compute waits drain only landed
// batches; A stays ~1.2 sub-steps in flight. Peak live ~124 VGPR <= the 128
// cap of launch_bounds(512,2): no spill, no collapse, by construction.
// ---------------------------------------------------------------------------
__global__ __launch_bounds__(512, 2) void gcn_agg_kernel(
    const float* __restrict__ adjA, const float* __restrict__ adjB,
    const __bf16* __restrict__ Bp, const float* __restrict__ bias,
    const float* __restrict__ prelu_a, float* __restrict__ out) {
  const int tid  = threadIdx.x;
  const int lane = tid & 63, w = tid >> 6;   // 8 waves; wave w -> cols [w*32,+32)
  const int llo  = lane & 15, lhi = lane >> 4;
  const int row0 = blockIdx.x * 32;
  const int z    = blockIdx.y;
  const float* __restrict__ adj = z ? adjB : adjA;

  __shared__ __align__(16) char LdsA[2][32768];   // 2 x (32 rows x 1 KB)

  v4f acc[2][2] = {};        // 16 VGPR
  v4f aA[4], aB[4];          // two A batches (4 rows x 1 KB each), 16+16

  auto issue_a = [&](int t, v4f (&ar)[4]) {
#pragma unroll
    for (int i = 0; i < 4; ++i) {
      const int r = w * 4 + i;
      const float* src =
          adj + (size_t)(row0 + r) * NROW + t * 256 + (lane << 2);
      ar[i] = *(const v4f*)src;
    }
  };
  // swizzled write: row r (1 KB, 64 slots of 16 B), phys slot = lane ^ key(r)
  auto write_a = [&](int buf, v4f (&ar)[4]) {
#pragma unroll
    for (int i = 0; i < 4; ++i) {
      const int r   = w * 4 + i;
      const int key = ((r & 15) << 1) | (r >> 4);
      *(v4f*)(&LdsA[buf][r * 1024 + ((lane ^ key) << 4)]) = ar[i];
    }
  };

  // B chunk = [4 kk][2 ci] = 32 VGPR; wave w's col-groups cig = w*2+ci.
  auto load_ch = [&](int t, int h, v8bf (&bb)[4][2]) {
#pragma unroll
    for (int kk = 0; kk < 4; ++kk)
#pragma unroll
      for (int ci = 0; ci < 2; ++ci)
        bb[kk][ci] = *(const v8bf*)(Bp +
            (((size_t)(t * 8 + h * 4 + kk) * 16 + w * 2 + ci) * 64 + lane) * 8);
  };

  auto compute_h = [&](int buf, int h, v8bf (&bb)[4][2]) {
    const char* ab = &LdsA[buf][0];
#pragma unroll
    for (int kk = 0; kk < 4; ++kk) {
      const int kg = h * 4 + kk;
      v8bf af[2];
#pragma unroll
      for (int rt = 0; rt < 2; ++rt) {
        const int r   = rt * 16 + llo;
        const int key = ((r & 15) << 1) | (r >> 4);
        const char* base = ab + r * 1024;
        v4f u0 = *(const v4f*)(base + (((kg * 8 + lhi * 2    ) ^ key) << 4));
        v4f u1 = *(const v4f*)(base + (((kg * 8 + lhi * 2 + 1) ^ key) << 4));
        af[rt] = cvt_bf8(u0, u1);
      }
#pragma unroll
      for (int ci = 0; ci < 2; ++ci)
#pragma unroll
        for (int rt = 0; rt < 2; ++rt)
          acc[rt][ci] = __builtin_amdgcn_mfma_f32_16x16x32_bf16(
              af[rt], bb[kk][ci], acc[rt][ci], 0, 0, 0);
    }
  };

  // prologue: aA=A(0), aB=A(1); A(0)->LDS0
  issue_a(0, aA);
  issue_a(1, aB);
  write_a(0, aA);                      // compiler waits aA only; aB in flight
  asm volatile("s_waitcnt lgkmcnt(0)" ::: "memory");
  __builtin_amdgcn_sched_barrier(0);
  __builtin_amdgcn_s_barrier();

  v8bf c0[4][2], c1[4][2];
#pragma unroll 1
  for (int t = 0; t < NSTEP; t += 2) {
    // ---- even sub-step: compute LDS0=A(t); refill aA=A(t+2); write aB->LDS1
    load_ch(t, 0, c0);                 // FIFO: aB, c0, c1, aA(t+2)
    load_ch(t, 1, c1);
    __builtin_amdgcn_sched_barrier(0);
    if (t + 2 < NSTEP) issue_a(t + 2, aA);
    __builtin_amdgcn_sched_barrier(0);
    compute_h(0, 0, c0);               // waits c0 -> drains aB (landed)
    compute_h(0, 1, c1);               // waits c1 -> aA untouched
    __builtin_amdgcn_sched_barrier(0);
    write_a(1, aB);                    // A(t+1) -> LDS1
    asm volatile("s_waitcnt lgkmcnt(0)" ::: "memory");
    __builtin_amdgcn_sched_barrier(0);
    __builtin_amdgcn_s_barrier();
    // ---- odd sub-step: compute LDS1=A(t+1); refill aB=A(t+3); write aA->LDS0
    load_ch(t + 1, 0, c0);             // FIFO: aA(t+2), c0, c1, aB(t+3)
    load_ch(t + 1, 1, c1);
    __builtin_amdgcn_sched_barrier(0);
    if (t + 3 < NSTEP) issue_a(t + 3, aB);
    __builtin_amdgcn_sched_barrier(0);
    compute_h(1, 0, c0);               // waits c0 -> drains aA (1 sub-step old)
    compute_h(1, 1, c1);
    __builtin_amdgcn_sched_barrier(0);
    if (t + 2 < NSTEP) {
      write_a(0, aA);                  // A(t+2) -> LDS0
      asm volatile("s_waitcnt lgkmcnt(0)" ::: "memory");
    }
    __builtin_amdgcn_sched_barrier(0);
    __builtin_amdgcn_s_barrier();
  }

  // epilogue: bias + prelu, direct store
  const float slope = prelu_a[0];
  float* __restrict__ outp = out + (size_t)z * M_ELEM;
#pragma unroll
  for (int ci = 0; ci < 2; ++ci) {
    const int o  = w * 32 + ci * 16 + llo;
    const float bs = bias[o];
#pragma unroll
    for (int rt = 0; rt < 2; ++rt) {
      const int m = row0 + rt * 16 + lhi * 4;
#pragma unroll
      for (int r = 0; r < 4; ++r) {
        float v = acc[rt][ci][r] + bs;
        outp[(size_t)(m + r) * OUTF + o] = v >= 0.f ? v : slope * v;
      }
    }
  }
}

extern "C" void kernel_launch(void* const* d_in, const int* in_sizes, int n_in,
                              void* d_out, int out_size, void* d_ws, size_t ws_size,
                              hipStream_t stream) {
  const float* feat = (const float*)d_in[0];
  const float* adj  = (const float*)d_in[1];
  const float* aug  = (const float*)d_in[2];
  const float* W    = (const float*)d_in[3];
  const float* bias = (const float*)d_in[4];
  const float* pa   = (const float*)d_in[5];
  float* out = (float*)d_out;
  __bf16* Bp = (__bf16*)d_ws;                    // 4 MB packed seq_fts

  seq_fts_kernel<<<dim3(NROW / 64), 256, 0, stream>>>(feat, W, Bp);
  gcn_agg_kernel<<<dim3(NROW / 32, 2), 512, 0, stream>>>(
      adj, aug, Bp, bias, pa, out);
}

// Round 17
// 176.823 us; speedup vs baseline: 1.3457x; 1.2896x over previous
//
#include <hip/hip_runtime.h>

#define NROW 8192
#define INF  512
#define OUTF 256
#define M_ELEM (NROW * OUTF)   // 2,097,152 f32 per output matrix
#define NSTEP 32               // K-steps of 256

typedef __bf16 v8bf __attribute__((ext_vector_type(8)));
typedef __bf16 v4bf __attribute__((ext_vector_type(4)));
typedef float  v4f  __attribute__((ext_vector_type(4)));

__device__ __forceinline__ v8bf cvt_bf8(v4f u0, v4f u1) {
  v8bf v;
  v[0]=(__bf16)u0[0]; v[1]=(__bf16)u0[1]; v[2]=(__bf16)u0[2]; v[3]=(__bf16)u0[3];
  v[4]=(__bf16)u1[0]; v[5]=(__bf16)u1[1]; v[6]=(__bf16)u1[2]; v[7]=(__bf16)u1[3];
  return v;
}

// ---------------------------------------------------------------------------
// Kernel A: seq = feat @ W^T, bf16 MFMA, output in B-fragment-packed layout:
//   elem(m,o) -> (((m>>5)*16 + (o>>4))*64 + ((m>>3)&3)*16 + (o&15))*8 + (m&7)
// ---------------------------------------------------------------------------
__global__ __launch_bounds__(256) void seq_fts_kernel(
    const float* __restrict__ feat, const float* __restrict__ W,
    __bf16* __restrict__ Bp) {
  const int tid  = threadIdx.x;
  const int lane = tid & 63, w = tid >> 6;
  const int llo  = lane & 15, lhi = lane >> 4;
  const int row0 = blockIdx.x * 64;
  const int col0 = w * 64;

  v4f acc[4][4] = {};
#pragma unroll 1
  for (int kb = 0; kb < INF / 32; ++kb) {
    const int kofs = kb * 32 + lhi * 8;
    v8bf a[4], b[4];
#pragma unroll
    for (int i = 0; i < 4; ++i) {
      const float* p = feat + (size_t)(row0 + i * 16 + llo) * INF + kofs;
      a[i] = cvt_bf8(*(const v4f*)p, *(const v4f*)(p + 4));
    }
#pragma unroll
    for (int i = 0; i < 4; ++i) {
      const float* p = W + (size_t)(col0 + i * 16 + llo) * INF + kofs;
      b[i] = cvt_bf8(*(const v4f*)p, *(const v4f*)(p + 4));
    }
#pragma unroll
    for (int ri = 0; ri < 4; ++ri)
#pragma unroll
      for (int ci = 0; ci < 4; ++ci)
        acc[ri][ci] = __builtin_amdgcn_mfma_f32_16x16x32_bf16(
            a[ri], b[ci], acc[ri][ci], 0, 0, 0);
  }
#pragma unroll
  for (int ri = 0; ri < 4; ++ri)
#pragma unroll
    for (int ci = 0; ci < 4; ++ci) {
      const int mf = row0 + ri * 16 + lhi * 4;
      const int o  = col0 + ci * 16 + llo;
      size_t e = (((size_t)(mf >> 5) * 16 + (o >> 4)) * 64 +
                  ((mf >> 3) & 3) * 16 + (o & 15)) * 8 + (mf & 7);
      v4bf v;
      v[0] = (__bf16)acc[ri][ci][0]; v[1] = (__bf16)acc[ri][ci][1];
      v[2] = (__bf16)acc[ri][ci][2]; v[3] = (__bf16)acc[ri][ci][3];
      *(v4bf*)(Bp + e) = v;
    }
}

// ---------------------------------------------------------------------------
// Kernel B: out = prelu(adj @ seq + bias).
// R14 structure EXACTLY (reg-staged A, NT, 1 KB extents, correct XOR key
// ((r&15)<<1)|((r>>3)&1), rolling 2-deep B regs, one raw barrier/step) with
// ONE delta: wave arrangement 2x4 -> 1x8. Each wave owns all 64 rows x 32
// DISTINCT cols -> B-fragment duplication eliminated (B issued per step/CU
// halves, 2 GB -> 1 GB per launch through L2/LLC). acc[4 rt][2 ci]=32 VGPR.
// ---------------------------------------------------------------------------
__global__ __launch_bounds__(512, 2)
__attribute__((amdgpu_waves_per_eu(2, 2)))
void gcn_agg_kernel(
    const float* __restrict__ adjA, const float* __restrict__ adjB,
    const __bf16* __restrict__ Bp, const float* __restrict__ bias,
    const float* __restrict__ prelu_a, float* __restrict__ out) {
  const int tid  = threadIdx.x;
  const int lane = tid & 63, w = tid >> 6;   // wave w -> cols [w*32, w*32+32)
  const int llo  = lane & 15, lhi = lane >> 4;
  const int row0 = blockIdx.x * 64;
  const int z    = blockIdx.y;
  const float* __restrict__ adj = z ? adjB : adjA;

  __shared__ __align__(16) char LdsA[2][65536];   // 2 x (64 rows x 1 KB)

  v4f acc[4][2] = {};        // 32 VGPR

  // --- A: 8 rows/wave, one 1 KB extent per row; lane l holds floats
  // [l*4, l*4+4) of the row (linear, coalesced, NT).
  v4f areg[8];
  auto issue_a = [&](int t) {
#pragma unroll
    for (int i = 0; i < 8; ++i) {
      const int r = w * 8 + i;
      const float* src =
          adj + (size_t)(row0 + r) * NROW + t * 256 + (lane << 2);
      areg[i] = __builtin_nontemporal_load((const v4f*)src);
    }
  };
  // swizzled write: LDS row r slot (l ^ key(r)) <- lane l's 16 B.
  auto write_a = [&](int buf) {
#pragma unroll
    for (int i = 0; i < 8; ++i) {
      const int r   = w * 8 + i;
      const int key = ((r & 15) << 1) | ((r >> 3) & 1);
      *(v4f*)(&LdsA[buf][r * 1024 + ((lane ^ key) << 4)]) = areg[i];
    }
  };

  // --- B fragments, kg granularity: [2 ci] = 16 VGPR per group (no dup:
  // wave w reads only col-groups w*2, w*2+1).
  const __bf16* __restrict__ Bpw = Bp + ((size_t)(w * 2) * 64 + lane) * 8;
  auto load_bg = [&](int t, int g, v8bf (&bb)[2]) {
#pragma unroll
    for (int ci = 0; ci < 2; ++ci)
      bb[ci] = *(const v8bf*)(
          Bpw + ((size_t)((t * 8 + g) * 16 + ci)) * 512);
  };

  auto compute_g = [&](int buf, int kg, v8bf (&bb)[2]) {
    const char* ab = &LdsA[buf][0];
    v8bf af[4];
#pragma unroll
    for (int rt = 0; rt < 4; ++rt) {
      const int r   = rt * 16 + llo;                  // bit3 = llo bit3: key
      const int key = ((r & 15) << 1) | ((r >> 3) & 1); // varies per lane
      const char* base = ab + r * 1024;
      v4f u0 = *(const v4f*)(base + (((kg * 8 + lhi * 2    ) ^ key) << 4));
      v4f u1 = *(const v4f*)(base + (((kg * 8 + lhi * 2 + 1) ^ key) << 4));
      af[rt] = cvt_bf8(u0, u1);
    }
#pragma unroll
    for (int ci = 0; ci < 2; ++ci)
#pragma unroll
      for (int rt = 0; rt < 4; ++rt)
        acc[rt][ci] = __builtin_amdgcn_mfma_f32_16x16x32_bf16(
            af[rt], bb[ci], acc[rt][ci], 0, 0, 0);
  };

  // prologue: A(0) -> LDS[0]
  issue_a(0);
  asm volatile("s_waitcnt vmcnt(0)" ::: "memory");
  write_a(0);
  asm volatile("s_waitcnt lgkmcnt(0)" ::: "memory");
  __builtin_amdgcn_s_barrier();

  v8bf b[2][2];
#pragma unroll 1
  for (int t = 0; t < NSTEP; ++t) {
    load_bg(t, 0, b[0]);                       // oldest
    __builtin_amdgcn_sched_barrier(0);
    load_bg(t, 1, b[1]);
    __builtin_amdgcn_sched_barrier(0);
    if (t + 1 < NSTEP) issue_a(t + 1);         // after bg0/bg1, before bg2
    __builtin_amdgcn_sched_barrier(0);
#pragma unroll
    for (int kg = 0; kg < 8; ++kg) {
      compute_g(t & 1, kg, b[kg & 1]);
      if (kg + 2 < 8) {
        __builtin_amdgcn_sched_barrier(0);
        load_bg(t, kg + 2, b[kg & 1]);
        __builtin_amdgcn_sched_barrier(0);
      }
    }
    __builtin_amdgcn_sched_barrier(0);
    if (t + 1 < NSTEP) {
      asm volatile("s_waitcnt vmcnt(0)" ::: "memory");  // A(t+1) landed
      write_a((t + 1) & 1);
      asm volatile("s_waitcnt lgkmcnt(0)" ::: "memory");
    }
    __builtin_amdgcn_s_barrier();
  }

  // epilogue: bias + prelu, direct store
  const float slope = prelu_a[0];
  float* __restrict__ outp = out + (size_t)z * M_ELEM;
#pragma unroll
  for (int ci = 0; ci < 2; ++ci) {
    const int o  = w * 32 + ci * 16 + llo;
    const float bs = bias[o];
#pragma unroll
    for (int rt = 0; rt < 4; ++rt) {
      const int m = row0 + rt * 16 + lhi * 4;
#pragma unroll
      for (int r = 0; r < 4; ++r) {
        float v = acc[rt][ci][r] + bs;
        outp[(size_t)(m + r) * OUTF + o] = v >= 0.f ? v : slope * v;
      }
    }
  }
}

extern "C" void kernel_launch(void* const* d_in, const int* in_sizes, int n_in,
                              void* d_out, int out_size, void* d_ws, size_t ws_size,
                              hipStream_t stream) {
  const float* feat = (const float*)d_in[0];
  const float* adj  = (const float*)d_in[1];
  const float* aug  = (const float*)d_in[2];
  const float* W    = (const float*)d_in[3];
  const float* bias = (const float*)d_in[4];
  const float* pa   = (const float*)d_in[5];
  float* out = (float*)d_out;
  __bf16* Bp = (__bf16*)d_ws;                    // 4 MB packed seq_fts

  seq_fts_kernel<<<dim3(NROW / 64), 256, 0, stream>>>(feat, W, Bp);
  gcn_agg_kernel<<<dim3(NROW / 64, 2), 512, 0, stream>>>(
      adj, aug, Bp, bias, pa, out);
}